// Round 3
// baseline (792.133 us; speedup 1.0000x reference)
//
#include <hip/hip_runtime.h>
#include <hip/hip_fp16.h>
#include <cstdint>
#include <cstddef>

#define B_SZ    200
#define NNZ_ALL 1070638
#define OUT_ALL 89064
#define NL      13
#define NBUCK   696    // ceil(OUT_ALL/128) slot-space buckets of 128 columns
#define EPB     8192   // edges per block in p1/p3
#define NBLK    131    // ceil(NNZ_ALL/EPB)
#define NSCAN   91176  // NBUCK*NBLK
#define NSB     357    // ceil(NSCAN/256)
#define KL_IDX  93800  // 200*469, KL scalar position in d_out
#define TTILES  6566   // 938*7 transpose tiles
#define GRID    1024   // co-resident: __launch_bounds__(256,4) => >=4 blocks/CU * 256 CU
#define NCELL   32

__constant__ int c_nnz_off[NL + 1] = {0, 480000, 540000, 780000, 810000, 930000, 945000,
                                      1005000, 1012500, 1042500, 1046250, 1061258, 1063134, 1070638};
__constant__ int c_out_off[NL + 1] = {0, 30000, 45000, 60000, 67500, 75000, 78750,
                                      82500, 84375, 86250, 87188, 88126, 88595, 89064};

// ---------------- threefry2x32 (matches jax._src.prng) ----------------
__device__ inline void tf2x32(uint32_t k0, uint32_t k1, uint32_t& x0, uint32_t& x1) {
  uint32_t ks2 = k0 ^ k1 ^ 0x1BD11BDAu;
  x0 += k0; x1 += k1;
#define TF_ROT(v, d) (((v) << (d)) | ((v) >> (32 - (d))))
#define TF_R4(a, b, c, dd)                                   \
  { x0 += x1; x1 = TF_ROT(x1, a);  x1 ^= x0;                 \
    x0 += x1; x1 = TF_ROT(x1, b);  x1 ^= x0;                 \
    x0 += x1; x1 = TF_ROT(x1, c);  x1 ^= x0;                 \
    x0 += x1; x1 = TF_ROT(x1, dd); x1 ^= x0; }
  TF_R4(13, 15, 26, 6);  x0 += k1;  x1 += ks2 + 1u;
  TF_R4(17, 29, 16, 24); x0 += ks2; x1 += k0  + 2u;
  TF_R4(13, 15, 26, 6);  x0 += k0;  x1 += k1  + 3u;
  TF_R4(17, 29, 16, 24); x0 += k1;  x1 += ks2 + 4u;
  TF_R4(13, 15, 26, 6);  x0 += ks2; x1 += k0  + 5u;
#undef TF_R4
#undef TF_ROT
}

__device__ inline float jax_uniform01(uint32_t k0, uint32_t k1, uint32_t i) {
  uint32_t x0 = 0u, x1 = i;
  tf2x32(k0, k1, x0, x1);
  uint32_t bits = x0 ^ x1;
  return __uint_as_float((bits >> 9) | 0x3f800000u) - 1.0f;
}

__device__ inline int edge_layer(int e) {
  int li = 0;
#pragma unroll
  for (int j = 1; j < NL; ++j) li += (e >= c_nnz_off[j]) ? 1 : 0;
  return li;
}

// ---------------- device-scope grid barrier ----------------
// cells: NCELL counters, 128B apart. gen: generation flag.
// release fence (buffer_wbl2) on arrival, acquire fence (buffer_inv) on release
// => identical cross-XCD visibility semantics to a kernel boundary.
__device__ inline void gbar(int* cells, int* gen, int phase) {
  __syncthreads();
  if (threadIdx.x < 64) {
    const int lane = threadIdx.x;
    if (lane == 0) {
      __builtin_amdgcn_fence(__ATOMIC_RELEASE, "agent");
      atomicAdd(&cells[(blockIdx.x & (NCELL - 1)) * 32], 1);
    }
    if (blockIdx.x == 0) {
      const int target = phase * GRID;
      long long guard = 0;
      for (;;) {
        int v = (lane < NCELL)
          ? __hip_atomic_load(&cells[lane * 32], __ATOMIC_RELAXED, __HIP_MEMORY_SCOPE_AGENT) : 0;
#pragma unroll
        for (int o = 32; o > 0; o >>= 1) v += __shfl_xor(v, o, 64);
        if (v >= target) break;
        if (++guard > (1LL << 21)) break;   // failsafe: terminate instead of hang
        __builtin_amdgcn_s_sleep(2);
      }
      __builtin_amdgcn_fence(__ATOMIC_ACQUIRE, "agent");
      if (lane == 0)
        __hip_atomic_store(gen, phase, __ATOMIC_RELEASE, __HIP_MEMORY_SCOPE_AGENT);
    } else {
      long long guard = 0;
      while (__hip_atomic_load(gen, __ATOMIC_RELAXED, __HIP_MEMORY_SCOPE_AGENT) < phase) {
        if (++guard > (1LL << 21)) break;   // failsafe
        __builtin_amdgcn_s_sleep(8);
      }
      __builtin_amdgcn_fence(__ATOMIC_ACQUIRE, "agent");
    }
  }
  __syncthreads();
}

// ---------------- gather core: wave-per-column, chunk-16 pipeline ----------------
__device__ inline void gather_wave(const uint2* __restrict__ hin4, const int2* __restrict__ rec,
                                   int e0, int e1, int t,
                                   float& a0, float& a1, float& a2, float& a3) {
  int e = e0;
  while (e + 16 <= e1) {
    int2 r[16];
    uint2 h[16];
#pragma unroll
    for (int i = 0; i < 16; ++i) r[i] = rec[e + i];
#pragma unroll
    for (int i = 0; i < 16; ++i) h[i] = hin4[r[i].x + t];
#pragma unroll
    for (int i = 0; i < 16; ++i) {
      float w = __int_as_float(r[i].y);
      __half2 lo = *reinterpret_cast<__half2*>(&h[i].x);
      __half2 hi = *reinterpret_cast<__half2*>(&h[i].y);
      float2 f01 = __half22float2(lo);
      float2 f23 = __half22float2(hi);
      a0 = fmaf(f01.x, w, a0); a1 = fmaf(f01.y, w, a1);
      a2 = fmaf(f23.x, w, a2); a3 = fmaf(f23.y, w, a3);
    }
    e += 16;
  }
  while (e + 4 <= e1) {
    int2 r[4];
    uint2 h[4];
#pragma unroll
    for (int i = 0; i < 4; ++i) r[i] = rec[e + i];
#pragma unroll
    for (int i = 0; i < 4; ++i) h[i] = hin4[r[i].x + t];
#pragma unroll
    for (int i = 0; i < 4; ++i) {
      float w = __int_as_float(r[i].y);
      __half2 lo = *reinterpret_cast<__half2*>(&h[i].x);
      __half2 hi = *reinterpret_cast<__half2*>(&h[i].y);
      float2 f01 = __half22float2(lo);
      float2 f23 = __half22float2(hi);
      a0 = fmaf(f01.x, w, a0); a1 = fmaf(f01.y, w, a1);
      a2 = fmaf(f23.x, w, a2); a3 = fmaf(f23.y, w, a3);
    }
    e += 4;
  }
  for (; e < e1; ++e) {
    int2 r = rec[e];
    float w = __int_as_float(r.y);
    uint2 h = hin4[r.x + t];
    __half2 lo = *reinterpret_cast<__half2*>(&h.x);
    __half2 hi = *reinterpret_cast<__half2*>(&h.y);
    float2 f01 = __half22float2(lo);
    float2 f23 = __half22float2(hi);
    a0 = fmaf(f01.x, w, a0); a1 = fmaf(f01.y, w, a1);
    a2 = fmaf(f23.x, w, a2); a3 = fmaf(f23.y, w, a3);
  }
}

__device__ inline uint2 pack4(float a0, float a1, float a2, float a3) {
  __half2 p0 = __float22half2_rn(make_float2(a0, a1));
  __half2 p1 = __float22half2_rn(make_float2(a2, a3));
  uint2 u;
  u.x = *reinterpret_cast<unsigned int*>(&p0);
  u.y = *reinterpret_cast<unsigned int*>(&p1);
  return u;
}

// ---------------- layer phase bodies (grid-strided over column groups) ----------------
__device__ inline void pool_phase(const __half* __restrict__ hin, __half* __restrict__ hout,
                                  const int* __restrict__ ptr, const int2* __restrict__ rec,
                                  const float* __restrict__ bias, int col_base, int S) {
  const int w = threadIdx.x >> 6;
  const int t = threadIdx.x & 63;
  const uint2* __restrict__ hin4 = (const uint2*)hin;
  const int items = (S + 3) >> 2;
  for (int vb = blockIdx.x; vb < items; vb += GRID) {
    const int d = vb * 4 + w;
    if (d < S && t < 50) {
      const int g = col_base + d;
      int e0 = ptr[g], e1 = ptr[g + 1];
      float bb = bias[g];
      float a0 = bb, a1 = bb, a2 = bb, a3 = bb;
      gather_wave(hin4, rec, e0, e1, t, a0, a1, a2, a3);
      ((uint2*)hout)[d * 50 + t] = pack4(a0, a1, a2, a3);
    }
  }
}

__device__ inline void lin_phase(const __half* __restrict__ hin, __half* __restrict__ hout,
                                 const int* __restrict__ ptr, const int2* __restrict__ rec,
                                 const float* __restrict__ bias, const float* __restrict__ gamma,
                                 const float* __restrict__ beta,
                                 int col_base, int bn_base, int S, int st) {
  const int w = threadIdx.x >> 6;
  const int t = threadIdx.x & 63;
  const uint2* __restrict__ hin4 = (const uint2*)hin;
  const int items = (S + 3) >> 2;
  // dropout key: fold_in(key(1234), 100+st)
  uint32_t k0 = 0u, k1 = (uint32_t)(100 + st);
  tf2x32(0u, 1234u, k0, k1);
  for (int vb = blockIdx.x; vb < items; vb += GRID) {
    const int d = vb * 4 + w;
    if (d < S) {  // uniform per wave -> shfl safe
      const int g = col_base + d;
      const int e0 = ptr[g], e1 = ptr[g + 1];
      float a0 = 0.f, a1 = 0.f, a2 = 0.f, a3 = 0.f;
      if (t < 50) {
        gather_wave(hin4, rec, e0, e1, t, a0, a1, a2, a3);
        float bb = bias[g];
        a0 += bb; a1 += bb; a2 += bb; a3 += bb;
      }
      float s = a0 + a1 + a2 + a3;
      float q = a0 * a0 + a1 * a1 + a2 * a2 + a3 * a3;
#pragma unroll
      for (int o = 32; o > 0; o >>= 1) { s += __shfl_xor(s, o, 64); q += __shfl_xor(q, o, 64); }
      float m = s * (1.0f / 200.0f);
      float v = q * (1.0f / 200.0f) - m * m;
      if (v < 0.f) v = 0.f;
      float rstd = 1.0f / sqrtf(v + 1e-5f);
      if (t < 50) {
        float ga = gamma[bn_base + d], be = beta[bn_base + d];
        float y0 = fmaf((a0 - m) * rstd, ga, be);
        float y1 = fmaf((a1 - m) * rstd, ga, be);
        float y2 = fmaf((a2 - m) * rstd, ga, be);
        float y3 = fmaf((a3 - m) * rstd, ga, be);
        y0 = y0 > 0.f ? y0 : 0.f;
        y1 = y1 > 0.f ? y1 : 0.f;
        y2 = y2 > 0.f ? y2 : 0.f;
        y3 = y3 > 0.f ? y3 : 0.f;
        uint32_t i0 = (uint32_t)((4 * t) * S + d);
        float r0 = jax_uniform01(k0, k1, i0);
        float r1 = jax_uniform01(k0, k1, i0 + (uint32_t)S);
        float r2 = jax_uniform01(k0, k1, i0 + (uint32_t)(2 * S));
        float r3 = jax_uniform01(k0, k1, i0 + (uint32_t)(3 * S));
        y0 = (r0 < 0.9f) ? y0 * (1.0f / 0.9f) : 0.f;
        y1 = (r1 < 0.9f) ? y1 * (1.0f / 0.9f) : 0.f;
        y2 = (r2 < 0.9f) ? y2 * (1.0f / 0.9f) : 0.f;
        y3 = (r3 < 0.9f) ? y3 * (1.0f / 0.9f) : 0.f;
        ((uint2*)hout)[d * 50 + t] = pack4(y0, y1, y2, y3);
      }
    }
  }
}

__device__ inline void final_phase(const __half* __restrict__ hin, float* __restrict__ out,
                                   const int* __restrict__ ptr, const int2* __restrict__ rec,
                                   const float* __restrict__ bias, int col_base) {
  const int w = threadIdx.x >> 6;
  const int t = threadIdx.x & 63;
  const uint2* __restrict__ hin4 = (const uint2*)hin;
  for (int vb = blockIdx.x; vb < 118; vb += GRID) {
    const int d = vb * 4 + w;
    if (d < 469) {
      const int g = col_base + d;
      const int e0 = ptr[g], e1 = ptr[g + 1];
      float a0 = 0.f, a1 = 0.f, a2 = 0.f, a3 = 0.f;
      if (t < 50) {
        gather_wave(hin4, rec, e0, e1, t, a0, a1, a2, a3);
        float bb = bias[g];
        a0 += bb; a1 += bb; a2 += bb; a3 += bb;
      }
      float s = a0 + a1 + a2 + a3;
      float q = a0 * a0 + a1 * a1 + a2 * a2 + a3 * a3;
#pragma unroll
      for (int o = 32; o > 0; o >>= 1) { s += __shfl_xor(s, o, 64); q += __shfl_xor(q, o, 64); }
      float m = s * (1.0f / 200.0f);
      float v = q * (1.0f / 200.0f) - m * m;
      if (v < 0.f) v = 0.f;
      float rstd = 1.0f / sqrtf(v + 1e-5f);
      if (t < 50) {
        out[(4 * t) * 469 + d]     = (a0 - m) * rstd;
        out[(4 * t + 1) * 469 + d] = (a1 - m) * rstd;
        out[(4 * t + 2) * 469 + d] = (a2 - m) * rstd;
        out[(4 * t + 3) * 469 + d] = (a3 - m) * rstd;
      }
    }
  }
}

// ---------------- the whole network in one persistent kernel ----------------
__global__ __launch_bounds__(256, 4) void mega_kernel(
    const float* __restrict__ x, const int* __restrict__ edges,
    const float* __restrict__ wmu, const float* __restrict__ wls,
    const float* __restrict__ bias, const float* __restrict__ gamma,
    const float* __restrict__ beta, float* __restrict__ out,
    __half* A, __half* Bf, __half* C,
    int* ptr, int* hist, int* start, int* bsums,
    int2* staging, int2* rec, int* bar) {
  const int* srcs = edges;
  const int* dsts = edges + NNZ_ALL;
  float* out_kl = out + KL_IDX;
  int* cells = bar;
  int* gen = bar + NCELL * 32;
  const int tid = threadIdx.x;

  __shared__ float t_tile[32][33];
  __shared__ int   s_buck[NBUCK];
  __shared__ int   s_scan[256];
  __shared__ int   s_f0[128], s_f1[128], s_f2[128];
  __shared__ int   s_i4[4];
  __shared__ float s_red[4];

  int ph = 0;

  // ---- P0: transpose (fp32 x -> fp16 col-major A) + p1 histogram ----
  for (int vb = blockIdx.x; vb < NBLK + TTILES; vb += GRID) {
    if (vb < NBLK) {
      for (int j = tid; j < NBUCK; j += 256) s_buck[j] = 0;
      __syncthreads();
      int e0 = vb * EPB, e1 = min(e0 + EPB, NNZ_ALL);
      for (int e = e0 + tid; e < e1; e += 256) {
        int li = edge_layer(e);
        int gcol = c_out_off[li] + dsts[e];
        atomicAdd(&s_buck[gcol >> 7], 1);
      }
      __syncthreads();
      for (int j = tid; j < NBUCK; j += 256) hist[j * NBLK + vb] = s_buck[j];
      __syncthreads();
    } else {
      int q = vb - NBLK;
      int s0 = (q % 938) * 32;
      int b0 = (q / 938) * 32;
      int tx = tid & 31, ty = tid >> 5;
#pragma unroll
      for (int j = 0; j < 4; ++j) {
        int b = b0 + ty + j * 8, s = s0 + tx;
        if (b < B_SZ && s < 30000) t_tile[ty + j * 8][tx] = x[b * 30000 + s];
      }
      __syncthreads();
#pragma unroll
      for (int j = 0; j < 4; ++j) {
        int s = s0 + ty + j * 8, b = b0 + tx;
        if (b < B_SZ && s < 30000) A[s * B_SZ + b] = __float2half(t_tile[tx][ty + j * 8]);
      }
      __syncthreads();
    }
  }
  gbar(cells, gen, ++ph);

  // ---- P1: scanA (per-256-block exclusive scan of hist) ----
  for (int vb = blockIdx.x; vb < NSB; vb += GRID) {
    int i = vb * 256 + tid;
    int v = (i < NSCAN) ? hist[i] : 0;
    s_scan[tid] = v;
    __syncthreads();
    for (int o = 1; o < 256; o <<= 1) {
      int add = (tid >= o) ? s_scan[tid - o] : 0;
      __syncthreads();
      s_scan[tid] += add;
      __syncthreads();
    }
    if (i < NSCAN) start[i] = s_scan[tid] - v;
    if (tid == 255) bsums[vb] = s_scan[255];
    __syncthreads();
  }
  gbar(cells, gen, ++ph);

  // ---- P2: scanBC (apply block-sum offsets) ----
  for (int vb = blockIdx.x; vb < NSB; vb += GRID) {
    int acc = 0;
    for (int j = tid; j < vb; j += 256) acc += bsums[j];
#pragma unroll
    for (int o = 32; o > 0; o >>= 1) acc += __shfl_xor(acc, o, 64);
    if ((tid & 63) == 0) s_i4[tid >> 6] = acc;
    __syncthreads();
    int off = s_i4[0] + s_i4[1] + s_i4[2] + s_i4[3];
    int i = vb * 256 + tid;
    if (i < NSCAN) start[i] += off;
    __syncthreads();
  }
  gbar(cells, gen, ++ph);

  // ---- P3: p3 (scatter edges into staging; KL accumulate) ----
  {
    float kl = 0.f;
    for (int vb = blockIdx.x; vb < NBLK; vb += GRID) {
      for (int j = tid; j < NBUCK; j += 256) s_buck[j] = start[j * NBLK + vb];
      __syncthreads();
      int e0 = vb * EPB, e1 = min(e0 + EPB, NNZ_ALL);
      for (int e = e0 + tid; e < e1; e += 256) {
        int li = edge_layer(e);
        int gcol = c_out_off[li] + dsts[e];
        float m = wmu[e], l = wls[e];
        kl += expf(2.f * l) + m * m - 1.f - 2.f * l;
        int pos = atomicAdd(&s_buck[gcol >> 7], 1);
        staging[pos] = make_int2(__float_as_int(m), (srcs[e] << 7) | (gcol & 127));
      }
      __syncthreads();
    }
#pragma unroll
    for (int o = 32; o > 0; o >>= 1) kl += __shfl_down(kl, o, 64);
    if ((tid & 63) == 0) s_red[tid >> 6] = kl;
    __syncthreads();
    if (tid == 0) {
      float k = s_red[0] + s_red[1] + s_red[2] + s_red[3];
      if (k != 0.f) atomicAdd(out_kl, 0.5f * k);
    }
    __syncthreads();
  }
  gbar(cells, gen, ++ph);

  // ---- P4: fin (per-bucket column sort -> rec/ptr) ----
  for (int vb = blockIdx.x; vb < NBUCK; vb += GRID) {
    int base = start[vb * NBLK];
    int end = (vb + 1 < NBUCK) ? start[(vb + 1) * NBLK] : NNZ_ALL;
    int colbase = vb << 7;
    int ncols = min(128, OUT_ALL - colbase);
    if (tid < 128) s_f0[tid] = 0;
    __syncthreads();
    for (int i = base + tid; i < end; i += 256) atomicAdd(&s_f0[staging[i].y & 127], 1);
    __syncthreads();
    if (tid < 128) s_f1[tid] = s_f0[tid];
    __syncthreads();
    for (int o = 1; o < 128; o <<= 1) {
      int add = (tid < 128 && tid >= o) ? s_f1[tid - o] : 0;
      __syncthreads();
      if (tid < 128) s_f1[tid] += add;
      __syncthreads();
    }
    if (tid < 128) {
      int excl = base + s_f1[tid] - s_f0[tid];
      s_f2[tid] = excl;
      if (tid < ncols) ptr[colbase + tid] = excl;
    }
    if (vb == NBUCK - 1 && tid == 0) ptr[OUT_ALL] = NNZ_ALL;
    __syncthreads();
    for (int i = base + tid; i < end; i += 256) {
      int2 v = staging[i];
      int p = atomicAdd(&s_f2[v.y & 127], 1);
      rec[p] = make_int2((v.y >> 7) * 50, v.x);   // pre-multiplied uint2 index
    }
    __syncthreads();
  }
  gbar(cells, gen, ++ph);

  // ---- layer chain ----
  lin_phase(A, Bf, ptr, rec, bias, gamma, beta, 0, 0, 30000, 0);          gbar(cells, gen, ++ph);
  pool_phase(Bf, C, ptr, rec, bias, 30000, 15000);                        gbar(cells, gen, ++ph);
  lin_phase(C, A, ptr, rec, bias, gamma, beta, 45000, 30000, 15000, 1);   gbar(cells, gen, ++ph);
  pool_phase(A, C, ptr, rec, bias, 60000, 7500);                          gbar(cells, gen, ++ph);
  lin_phase(C, Bf, ptr, rec, bias, gamma, beta, 67500, 45000, 7500, 2);   gbar(cells, gen, ++ph);
  pool_phase(Bf, C, ptr, rec, bias, 75000, 3750);                         gbar(cells, gen, ++ph);
  lin_phase(C, A, ptr, rec, bias, gamma, beta, 78750, 52500, 3750, 3);    gbar(cells, gen, ++ph);
  pool_phase(A, C, ptr, rec, bias, 82500, 1875);                          gbar(cells, gen, ++ph);
  lin_phase(C, Bf, ptr, rec, bias, gamma, beta, 84375, 56250, 1875, 4);   gbar(cells, gen, ++ph);
  pool_phase(Bf, C, ptr, rec, bias, 86250, 938);                          gbar(cells, gen, ++ph);
  lin_phase(C, A, ptr, rec, bias, gamma, beta, 87188, 58125, 938, 5);     gbar(cells, gen, ++ph);
  pool_phase(A, C, ptr, rec, bias, 88126, 469);                           gbar(cells, gen, ++ph);
  final_phase(C, out, ptr, rec, bias, 88595);
}

extern "C" void kernel_launch(void* const* d_in, const int* in_sizes, int n_in,
                              void* d_out, int out_size, void* d_ws, size_t ws_size,
                              hipStream_t stream) {
  const float* x     = (const float*)d_in[0];
  const int*   edges = (const int*)d_in[1];
  const float* wmu   = (const float*)d_in[2];
  const float* wls   = (const float*)d_in[3];
  const float* bias  = (const float*)d_in[4];
  const float* gamma = (const float*)d_in[5];
  const float* beta  = (const float*)d_in[6];
  float* out = (float*)d_out;

  char* p = (char*)d_ws;
  auto alloc = [&](size_t bytes) { char* r = p; p += (bytes + 255) & ~(size_t)255; return r; };
  __half* A      = (__half*)alloc((size_t)6000000 * 2);   // 30000 cols x 200, fp16
  __half* Bf     = (__half*)alloc((size_t)6000000 * 2);
  __half* C      = (__half*)alloc((size_t)3000000 * 2);
  int*   ptr     = (int*)alloc((size_t)(OUT_ALL + 1) * 4);
  int*   hist    = (int*)alloc((size_t)NSCAN * 4);
  int*   start   = (int*)alloc((size_t)NSCAN * 4);
  int*   bsums   = (int*)alloc((size_t)512 * 4);
  int2*  staging = (int2*)alloc((size_t)NNZ_ALL * 8);
  int2*  rec     = (int2*)alloc((size_t)NNZ_ALL * 8);
  int*   bar     = (int*)alloc((size_t)(NCELL * 32 + 32) * 4);

  hipMemsetAsync(bar, 0, (size_t)(NCELL * 32 + 32) * 4, stream);
  hipMemsetAsync(out + KL_IDX, 0, 4, stream);

  mega_kernel<<<GRID, 256, 0, stream>>>(x, edges, wmu, wls, bias, gamma, beta, out,
                                        A, Bf, C, ptr, hist, start, bsums, staging, rec, bar);
}

// Round 4
// 289.396 us; speedup vs baseline: 2.7372x; 2.7372x over previous
//
#include <hip/hip_runtime.h>
#include <hip/hip_fp16.h>
#include <cstdint>
#include <cstddef>

#define B_SZ    200
#define NNZ_ALL 1070638
#define OUT_ALL 89064
#define NL      13
#define NBUCK   696    // ceil(OUT_ALL/128) slot-space buckets of 128 columns
#define EPB     8192   // edges per block in p1/p3
#define NBLK    131    // ceil(NNZ_ALL/EPB)
#define NSCAN   91176  // NBUCK*NBLK
#define NSB     357    // ceil(NSCAN/256)
#define KL_IDX  93800  // 200*469, KL scalar position in d_out
#define TGRID   6566   // 938*7 transpose tiles

__constant__ int c_nnz_off[NL + 1] = {0, 480000, 540000, 780000, 810000, 930000, 945000,
                                      1005000, 1012500, 1042500, 1046250, 1061258, 1063134, 1070638};
__constant__ int c_out_off[NL + 1] = {0, 30000, 45000, 60000, 67500, 75000, 78750,
                                      82500, 84375, 86250, 87188, 88126, 88595, 89064};

// ---------------- threefry2x32 (matches jax._src.prng) ----------------
__host__ __device__ inline void tf2x32(uint32_t k0, uint32_t k1, uint32_t& x0, uint32_t& x1) {
  uint32_t ks2 = k0 ^ k1 ^ 0x1BD11BDAu;
  x0 += k0; x1 += k1;
#define TF_ROT(v, d) (((v) << (d)) | ((v) >> (32 - (d))))
#define TF_R4(a, b, c, dd)                                   \
  { x0 += x1; x1 = TF_ROT(x1, a);  x1 ^= x0;                 \
    x0 += x1; x1 = TF_ROT(x1, b);  x1 ^= x0;                 \
    x0 += x1; x1 = TF_ROT(x1, c);  x1 ^= x0;                 \
    x0 += x1; x1 = TF_ROT(x1, dd); x1 ^= x0; }
  TF_R4(13, 15, 26, 6);  x0 += k1;  x1 += ks2 + 1u;
  TF_R4(17, 29, 16, 24); x0 += ks2; x1 += k0  + 2u;
  TF_R4(13, 15, 26, 6);  x0 += k0;  x1 += k1  + 3u;
  TF_R4(17, 29, 16, 24); x0 += k1;  x1 += ks2 + 4u;
  TF_R4(13, 15, 26, 6);  x0 += ks2; x1 += k0  + 5u;
#undef TF_R4
#undef TF_ROT
}

// partitionable threefry random bits for 32-bit: bits_i = o0 ^ o1, counter i (hi=0)
__device__ inline float jax_uniform01(uint32_t k0, uint32_t k1, uint32_t i) {
  uint32_t x0 = 0u, x1 = i;
  tf2x32(k0, k1, x0, x1);
  uint32_t bits = x0 ^ x1;
  return __uint_as_float((bits >> 9) | 0x3f800000u) - 1.0f;
}

__device__ inline int edge_layer(int e) {
  int li = 0;
#pragma unroll
  for (int j = 1; j < NL; ++j) li += (e >= c_nnz_off[j]) ? 1 : 0;
  return li;
}

// ---------------- fused: transpose x -> fp16 col-major  +  p1 histogram ----------------
// blocks [0, NBLK)          : p1 role (per-chunk bucket histogram)
// blocks [NBLK, NBLK+TGRID) : transpose role (32x32 tiles)
__global__ __launch_bounds__(256) void transpose_p1_kernel(
    const float* __restrict__ x, __half* __restrict__ xt,
    const int* __restrict__ dsts, int* __restrict__ hist, float* __restrict__ out_kl) {
  int bid = blockIdx.x;
  if (bid < NBLK) {
    __shared__ int cnt[NBUCK];
    if (bid == 0 && threadIdx.x == 0) out_kl[0] = 0.0f;
    for (int j = threadIdx.x; j < NBUCK; j += 256) cnt[j] = 0;
    __syncthreads();
    int e0 = bid * EPB;
    int e1 = min(e0 + EPB, NNZ_ALL);
    for (int e = e0 + threadIdx.x; e < e1; e += 256) {
      int li = edge_layer(e);
      int gcol = c_out_off[li] + dsts[e];
      atomicAdd(&cnt[gcol >> 7], 1);
    }
    __syncthreads();
    for (int j = threadIdx.x; j < NBUCK; j += 256) hist[j * NBLK + bid] = cnt[j];
  } else {
    __shared__ float tile[32][33];
    int q = bid - NBLK;
    int s0 = (q % 938) * 32;
    int b0 = (q / 938) * 32;
    int tx = threadIdx.x & 31;
    int ty = threadIdx.x >> 5;   // 0..7
#pragma unroll
    for (int j = 0; j < 4; ++j) {
      int b = b0 + ty + j * 8;
      int s = s0 + tx;
      if (b < B_SZ && s < 30000) tile[ty + j * 8][tx] = x[b * 30000 + s];
    }
    __syncthreads();
#pragma unroll
    for (int j = 0; j < 4; ++j) {
      int s = s0 + ty + j * 8;
      int b = b0 + tx;
      if (b < B_SZ && s < 30000) xt[s * B_SZ + b] = __float2half(tile[tx][ty + j * 8]);
    }
  }
}

__global__ void scanA_kernel(const int* __restrict__ hist, int* __restrict__ start,
                             int* __restrict__ bsums) {
  __shared__ int sh[256];
  int t = threadIdx.x;
  int i = blockIdx.x * 256 + t;
  int v = (i < NSCAN) ? hist[i] : 0;
  sh[t] = v;
  __syncthreads();
  for (int o = 1; o < 256; o <<= 1) {
    int add = (t >= o) ? sh[t - o] : 0;
    __syncthreads();
    sh[t] += add;
    __syncthreads();
  }
  if (i < NSCAN) start[i] = sh[t] - v;
  if (t == 255) bsums[blockIdx.x] = sh[255];
}

// fused scanB+scanC: each block sums bsums[0..bid) (<=357 ints) and applies the offset
__global__ __launch_bounds__(256) void scanBC_kernel(int* __restrict__ start,
                                                     const int* __restrict__ bsums) {
  int bid = blockIdx.x;
  int t = threadIdx.x;
  int acc = 0;
  for (int j = t; j < bid; j += 256) acc += bsums[j];
#pragma unroll
  for (int o = 32; o > 0; o >>= 1) acc += __shfl_xor(acc, o, 64);
  __shared__ int sh[4];
  if ((t & 63) == 0) sh[t >> 6] = acc;
  __syncthreads();
  int off = sh[0] + sh[1] + sh[2] + sh[3];
  int i = bid * 256 + t;
  if (i < NSCAN) start[i] += off;
}

// p3: place edges into private (block,bucket) staging sub-ranges via LDS cursors.
__global__ __launch_bounds__(256) void p3_kernel(
    const int* __restrict__ dsts, const int* __restrict__ srcs,
    const float* __restrict__ wmu, const float* __restrict__ wls,
    const int* __restrict__ start, int2* __restrict__ staging, float* __restrict__ out_kl) {
  __shared__ int cur[NBUCK];
  for (int j = threadIdx.x; j < NBUCK; j += 256) cur[j] = start[j * NBLK + blockIdx.x];
  __syncthreads();
  int e0 = blockIdx.x * EPB;
  int e1 = min(e0 + EPB, NNZ_ALL);
  float kl = 0.f;
  for (int e = e0 + threadIdx.x; e < e1; e += 256) {
    int li = edge_layer(e);
    int gcol = c_out_off[li] + dsts[e];
    float m = wmu[e], l = wls[e];
    kl += expf(2.f * l) + m * m - 1.f - 2.f * l;
    int pos = atomicAdd(&cur[gcol >> 7], 1);
    staging[pos] = make_int2(__float_as_int(m), (srcs[e] << 7) | (gcol & 127));
  }
#pragma unroll
  for (int o = 32; o > 0; o >>= 1) kl += __shfl_down(kl, o, 64);
  __shared__ float sh[4];
  if ((threadIdx.x & 63) == 0) sh[threadIdx.x >> 6] = kl;
  __syncthreads();
  if (threadIdx.x == 0) atomicAdd(out_kl, 0.5f * (sh[0] + sh[1] + sh[2] + sh[3]));
}

// finalize: per bucket, count columns, write ptr[], reorder staging -> rec {src*50, w}
__global__ __launch_bounds__(256) void fin_kernel(const int* __restrict__ start,
                                                  const int2* __restrict__ staging,
                                                  int2* __restrict__ rec, int* __restrict__ ptr) {
  int b = blockIdx.x;
  int base = start[b * NBLK];
  int end = (b + 1 < NBUCK) ? start[(b + 1) * NBLK] : NNZ_ALL;
  int colbase = b << 7;
  int ncols = min(128, OUT_ALL - colbase);
  __shared__ int cnt[128], sc[128], cur[128];
  int t = threadIdx.x;
  if (t < 128) cnt[t] = 0;
  __syncthreads();
  for (int i = base + t; i < end; i += 256) atomicAdd(&cnt[staging[i].y & 127], 1);
  __syncthreads();
  if (t < 128) sc[t] = cnt[t];
  __syncthreads();
  for (int o = 1; o < 128; o <<= 1) {
    int add = (t < 128 && t >= o) ? sc[t - o] : 0;
    __syncthreads();
    if (t < 128) sc[t] += add;
    __syncthreads();
  }
  if (t < 128) {
    int excl = base + sc[t] - cnt[t];
    cur[t] = excl;
    if (t < ncols) ptr[colbase + t] = excl;
  }
  if (b == NBUCK - 1 && t == 0) ptr[OUT_ALL] = NNZ_ALL;
  __syncthreads();
  for (int i = base + t; i < end; i += 256) {
    int2 v = staging[i];
    int p = atomicAdd(&cur[v.y & 127], 1);
    rec[p] = make_int2((v.y >> 7) * 50, v.x);   // pre-multiplied uint2 (4-half) index
  }
}

// ---------------- gather core: wave-per-column, chunk-16 pipeline ----------------
// thread t<50 handles batch elements 4t..4t+3 (one uint2 = 4 halves per edge)
__device__ inline void gather_wave(const uint2* __restrict__ hin4, const int2* __restrict__ rec,
                                   int e0, int e1, int t,
                                   float& a0, float& a1, float& a2, float& a3) {
  int e = e0;
  while (e + 16 <= e1) {
    int2 r[16];
    uint2 h[16];
#pragma unroll
    for (int i = 0; i < 16; ++i) r[i] = rec[e + i];
#pragma unroll
    for (int i = 0; i < 16; ++i) h[i] = hin4[r[i].x + t];
#pragma unroll
    for (int i = 0; i < 16; ++i) {
      float w = __int_as_float(r[i].y);
      __half2 lo = *reinterpret_cast<__half2*>(&h[i].x);
      __half2 hi = *reinterpret_cast<__half2*>(&h[i].y);
      float2 f01 = __half22float2(lo);
      float2 f23 = __half22float2(hi);
      a0 = fmaf(f01.x, w, a0); a1 = fmaf(f01.y, w, a1);
      a2 = fmaf(f23.x, w, a2); a3 = fmaf(f23.y, w, a3);
    }
    e += 16;
  }
  while (e + 4 <= e1) {
    int2 r[4];
    uint2 h[4];
#pragma unroll
    for (int i = 0; i < 4; ++i) r[i] = rec[e + i];
#pragma unroll
    for (int i = 0; i < 4; ++i) h[i] = hin4[r[i].x + t];
#pragma unroll
    for (int i = 0; i < 4; ++i) {
      float w = __int_as_float(r[i].y);
      __half2 lo = *reinterpret_cast<__half2*>(&h[i].x);
      __half2 hi = *reinterpret_cast<__half2*>(&h[i].y);
      float2 f01 = __half22float2(lo);
      float2 f23 = __half22float2(hi);
      a0 = fmaf(f01.x, w, a0); a1 = fmaf(f01.y, w, a1);
      a2 = fmaf(f23.x, w, a2); a3 = fmaf(f23.y, w, a3);
    }
    e += 4;
  }
  for (; e < e1; ++e) {
    int2 r = rec[e];
    float w = __int_as_float(r.y);
    uint2 h = hin4[r.x + t];
    __half2 lo = *reinterpret_cast<__half2*>(&h.x);
    __half2 hi = *reinterpret_cast<__half2*>(&h.y);
    float2 f01 = __half22float2(lo);
    float2 f23 = __half22float2(hi);
    a0 = fmaf(f01.x, w, a0); a1 = fmaf(f01.y, w, a1);
    a2 = fmaf(f23.x, w, a2); a3 = fmaf(f23.y, w, a3);
  }
}

__device__ inline uint2 pack4(float a0, float a1, float a2, float a3) {
  __half2 p0 = __float22half2_rn(make_float2(a0, a1));
  __half2 p1 = __float22half2_rn(make_float2(a2, a3));
  uint2 u;
  u.x = *reinterpret_cast<unsigned int*>(&p0);
  u.y = *reinterpret_cast<unsigned int*>(&p1);
  return u;
}

// ---------------- pool layer (sparse gather + bias only), wave-per-column ----------------
__global__ __launch_bounds__(256) void pool_kernel(
    const __half* __restrict__ hin, __half* __restrict__ hout,
    const int* __restrict__ ptr, const int2* __restrict__ rec,
    const float* __restrict__ bias, int col_base, int S) {
  const int w = threadIdx.x >> 6;
  const int t = threadIdx.x & 63;
  const int d = blockIdx.x * 4 + w;
  if (d >= S || t >= 50) return;
  const int g = col_base + d;
  int e0 = ptr[g], e1 = ptr[g + 1];
  const uint2* __restrict__ hin4 = (const uint2*)hin;
  float bb = bias[g];
  float a0 = bb, a1 = bb, a2 = bb, a3 = bb;
  gather_wave(hin4, rec, e0, e1, t, a0, a1, a2, a3);
  ((uint2*)hout)[d * 50 + t] = pack4(a0, a1, a2, a3);
}

// ---------------- lin layer fused with BN + ReLU + dropout, wave-per-column ----------------
__global__ __launch_bounds__(256) void lin_bn_drop_kernel(
    const __half* __restrict__ hin, __half* __restrict__ hout,
    const int* __restrict__ ptr, const int2* __restrict__ rec,
    const float* __restrict__ bias, const float* __restrict__ gamma, const float* __restrict__ beta,
    int col_base, int bn_base, int S, uint32_t k0, uint32_t k1) {
  const int w = threadIdx.x >> 6;
  const int t = threadIdx.x & 63;
  const int d = blockIdx.x * 4 + w;
  if (d >= S) return;
  const int g = col_base + d;
  const int e0 = ptr[g], e1 = ptr[g + 1];
  const uint2* __restrict__ hin4 = (const uint2*)hin;
  float a0 = 0.f, a1 = 0.f, a2 = 0.f, a3 = 0.f;
  if (t < 50) {
    gather_wave(hin4, rec, e0, e1, t, a0, a1, a2, a3);
    float bb = bias[g];
    a0 += bb; a1 += bb; a2 += bb; a3 += bb;
  }
  // wave-local butterfly reduction over 200 values (lanes >=50 contribute 0)
  float s = a0 + a1 + a2 + a3;
  float q = a0 * a0 + a1 * a1 + a2 * a2 + a3 * a3;
#pragma unroll
  for (int o = 32; o > 0; o >>= 1) { s += __shfl_xor(s, o, 64); q += __shfl_xor(q, o, 64); }
  float m = s * (1.0f / 200.0f);
  float v = q * (1.0f / 200.0f) - m * m;
  if (v < 0.f) v = 0.f;
  float rstd = 1.0f / sqrtf(v + 1e-5f);
  if (t < 50) {
    float ga = gamma[bn_base + d], be = beta[bn_base + d];
    float y0 = fmaf((a0 - m) * rstd, ga, be);
    float y1 = fmaf((a1 - m) * rstd, ga, be);
    float y2 = fmaf((a2 - m) * rstd, ga, be);
    float y3 = fmaf((a3 - m) * rstd, ga, be);
    y0 = y0 > 0.f ? y0 : 0.f;
    y1 = y1 > 0.f ? y1 : 0.f;
    y2 = y2 > 0.f ? y2 : 0.f;
    y3 = y3 > 0.f ? y3 : 0.f;
    uint32_t i0 = (uint32_t)((4 * t) * S + d);
    float r0 = jax_uniform01(k0, k1, i0);
    float r1 = jax_uniform01(k0, k1, i0 + (uint32_t)S);
    float r2 = jax_uniform01(k0, k1, i0 + (uint32_t)(2 * S));
    float r3 = jax_uniform01(k0, k1, i0 + (uint32_t)(3 * S));
    y0 = (r0 < 0.9f) ? y0 * (1.0f / 0.9f) : 0.f;
    y1 = (r1 < 0.9f) ? y1 * (1.0f / 0.9f) : 0.f;
    y2 = (r2 < 0.9f) ? y2 * (1.0f / 0.9f) : 0.f;
    y3 = (r3 < 0.9f) ? y3 * (1.0f / 0.9f) : 0.f;
    ((uint2*)hout)[d * 50 + t] = pack4(y0, y1, y2, y3);
  }
}

// ---------------- final lin + plain BN, fp16 in, fp32 row-major out ----------------
__global__ __launch_bounds__(256) void final_bn_kernel(
    const __half* __restrict__ hin, float* __restrict__ out,
    const int* __restrict__ ptr, const int2* __restrict__ rec,
    const float* __restrict__ bias, int col_base) {
  const int w = threadIdx.x >> 6;
  const int t = threadIdx.x & 63;
  const int d = blockIdx.x * 4 + w;
  if (d >= 469) return;
  const int g = col_base + d;
  const int e0 = ptr[g], e1 = ptr[g + 1];
  const uint2* __restrict__ hin4 = (const uint2*)hin;
  float a0 = 0.f, a1 = 0.f, a2 = 0.f, a3 = 0.f;
  if (t < 50) {
    gather_wave(hin4, rec, e0, e1, t, a0, a1, a2, a3);
    float bb = bias[g];
    a0 += bb; a1 += bb; a2 += bb; a3 += bb;
  }
  float s = a0 + a1 + a2 + a3;
  float q = a0 * a0 + a1 * a1 + a2 * a2 + a3 * a3;
#pragma unroll
  for (int o = 32; o > 0; o >>= 1) { s += __shfl_xor(s, o, 64); q += __shfl_xor(q, o, 64); }
  float m = s * (1.0f / 200.0f);
  float v = q * (1.0f / 200.0f) - m * m;
  if (v < 0.f) v = 0.f;
  float rstd = 1.0f / sqrtf(v + 1e-5f);
  if (t < 50) {
    out[(4 * t) * 469 + d]     = (a0 - m) * rstd;
    out[(4 * t + 1) * 469 + d] = (a1 - m) * rstd;
    out[(4 * t + 2) * 469 + d] = (a2 - m) * rstd;
    out[(4 * t + 3) * 469 + d] = (a3 - m) * rstd;
  }
}

extern "C" void kernel_launch(void* const* d_in, const int* in_sizes, int n_in,
                              void* d_out, int out_size, void* d_ws, size_t ws_size,
                              hipStream_t stream) {
  const float* x     = (const float*)d_in[0];
  const int*   edges = (const int*)d_in[1];
  const float* wmu   = (const float*)d_in[2];
  const float* wls   = (const float*)d_in[3];
  const float* bias  = (const float*)d_in[4];
  const float* gamma = (const float*)d_in[5];
  const float* beta  = (const float*)d_in[6];
  float* out = (float*)d_out;
  const int* srcs = edges;
  const int* dsts = edges + NNZ_ALL;

  char* p = (char*)d_ws;
  auto alloc = [&](size_t bytes) { char* r = p; p += (bytes + 255) & ~(size_t)255; return r; };
  __half* A      = (__half*)alloc((size_t)6000000 * 2);   // 30000 cols x 200, fp16
  __half* Bf     = (__half*)alloc((size_t)6000000 * 2);
  __half* C      = (__half*)alloc((size_t)3000000 * 2);
  int*   ptr     = (int*)alloc((size_t)(OUT_ALL + 1) * 4);
  int*   hist    = (int*)alloc((size_t)NSCAN * 4);
  int*   start   = (int*)alloc((size_t)NSCAN * 4);
  int*   bsums   = (int*)alloc((size_t)512 * 4);
  int2*  staging = (int2*)alloc((size_t)NNZ_ALL * 8);
  int2*  rec     = (int2*)alloc((size_t)NNZ_ALL * 8);

  // stage dropout keys: fold_in(key(1234), 100+st) = threefry2x32((0,1234),(0,100+st))
  uint32_t k0s[6], k1s[6];
  for (int st = 0; st < 6; ++st) {
    uint32_t a = 0u, b = (uint32_t)(100 + st);
    tf2x32(0u, 1234u, a, b);
    k0s[st] = a; k1s[st] = b;
  }

  transpose_p1_kernel<<<NBLK + TGRID, 256, 0, stream>>>(x, A, dsts, hist, out + KL_IDX);
  scanA_kernel<<<NSB, 256, 0, stream>>>(hist, start, bsums);
  scanBC_kernel<<<NSB, 256, 0, stream>>>(start, bsums);
  p3_kernel<<<NBLK, 256, 0, stream>>>(dsts, srcs, wmu, wls, start, staging, out + KL_IDX);
  fin_kernel<<<NBUCK, 256, 0, stream>>>(start, staging, rec, ptr);

  const int S[7]        = {30000, 15000, 7500, 3750, 1875, 938, 469};
  const int OUT_OFF[14] = {0, 30000, 45000, 60000, 67500, 75000, 78750,
                           82500, 84375, 86250, 87188, 88126, 88595, 89064};
  const int BN_OFF[7]   = {0, 30000, 45000, 52500, 56250, 58125, 59063};

  lin_bn_drop_kernel<<<7500, 256, 0, stream>>>(A, Bf, ptr, rec, bias, gamma, beta,
                                               OUT_OFF[0], BN_OFF[0], S[0], k0s[0], k1s[0]);
  __half* cur = Bf;
  __half* alt = A;
  for (int st = 1; st <= 5; ++st) {
    int li_p = 2 * st - 1, li_l = 2 * st;
    int nb = (S[st] + 3) / 4;
    pool_kernel<<<nb, 256, 0, stream>>>(cur, C, ptr, rec, bias, OUT_OFF[li_p], S[st]);
    lin_bn_drop_kernel<<<nb, 256, 0, stream>>>(C, alt, ptr, rec, bias, gamma, beta,
                                               OUT_OFF[li_l], BN_OFF[st], S[st],
                                               k0s[st], k1s[st]);
    __half* tmp = cur; cur = alt; alt = tmp;
  }
  pool_kernel<<<118, 256, 0, stream>>>(cur, C, ptr, rec, bias, OUT_OFF[11], 469);
  final_bn_kernel<<<118, 256, 0, stream>>>(C, out, ptr, rec, bias, OUT_OFF[12]);
}